// Round 2
// baseline (2731.359 us; speedup 1.0000x reference)
//
#include <hip/hip_runtime.h>

#define NN 100000
#define NE 1600000
#define NG 256

// ---------------------------------------------------------------------------
// Workspace layout (4-byte words). All buffers 16B-aligned (offsets % 4 == 0).
//   norm_out  : [0, NN)                      float
//   norm_in   : [NN, 2NN)                    float
//   inv_cnt   : [2NN, 2NN+256)               float
//   counts    : [2NN+256, 2NN+512)           int
//   row_ptr   : [2NN+512, 3NN+516)           int (NN+1 used, padded)
//   csr_src   : [3NN+516, +NE)               int
//   agg       : [A, A+32NN)                  float (setup aliases: hist_src=A,
//                                            hist_dst=A+NN, next=A+2NN)
//   buf       : [B, B+32NN)                  float (xs0 -> xs1 -> xs2)
// total = 67*NN + NE + 516 words ~= 33.2 MB
// ---------------------------------------------------------------------------
#define OFF_NORM_OUT 0
#define OFF_NORM_IN  (NN)
#define OFF_INVC     (2 * NN)
#define OFF_COUNTS   (2 * NN + 256)
#define OFF_ROWPTR   (2 * NN + 512)
#define OFF_CSR      (3 * NN + 516)
#define OFF_AGG      (3 * NN + 516 + NE)
#define OFF_BUF      (3 * NN + 516 + NE + 32 * NN)

__global__ void k_hist(const int* __restrict__ src, const int* __restrict__ dst,
                       int* __restrict__ hist_src, int* __restrict__ hist_dst) {
  int e = blockIdx.x * blockDim.x + threadIdx.x;
  if (e < NE) {
    atomicAdd(&hist_src[src[e]], 1);
    atomicAdd(&hist_dst[dst[e]], 1);
  }
}

// single-block exclusive scan of hist_dst -> row_ptr (and a copy into next)
#define SCAN_T 1024
__global__ void __launch_bounds__(SCAN_T) k_scan(const int* __restrict__ hist,
                                                 int* __restrict__ row_ptr,
                                                 int* __restrict__ next) {
  __shared__ int ssum[SCAN_T];
  int t = threadIdx.x;
  constexpr int CH = (NN + SCAN_T - 1) / SCAN_T;  // 98
  int lo = t * CH;
  int hi = min(lo + CH, NN);
  int s = 0;
  for (int i = lo; i < hi; ++i) s += hist[i];
  ssum[t] = s;
  __syncthreads();
  int incl = s;
  for (int off = 1; off < SCAN_T; off <<= 1) {
    int o = (t >= off) ? ssum[t - off] : 0;
    __syncthreads();
    incl += o;
    ssum[t] = incl;
    __syncthreads();
  }
  int base = incl - s;  // exclusive prefix
  for (int i = lo; i < hi; ++i) {
    row_ptr[i] = base;
    next[i] = base;
    base += hist[i];
  }
  if (t == 0) row_ptr[NN] = NE;
}

__global__ void k_fill(const int* __restrict__ src, const int* __restrict__ dst,
                       int* __restrict__ next, int* __restrict__ csr) {
  int e = blockIdx.x * blockDim.x + threadIdx.x;
  if (e < NE) {
    int slot = atomicAdd(&next[dst[e]], 1);
    csr[slot] = src[e];
  }
}

// norms from int degree hists, xs0 = n_feat * norm_out, graph histogram
__global__ void k_norm_scale(const float* __restrict__ n_feat, const int* __restrict__ gid,
                             const int* __restrict__ hist_src, const int* __restrict__ hist_dst,
                             float* __restrict__ norm_out, float* __restrict__ norm_in,
                             int* __restrict__ counts, float* __restrict__ xs) {
  int i = blockIdx.x * blockDim.x + threadIdx.x;
  if (i >= NN) return;
  int dgo = hist_src[i];
  float no = dgo > 0 ? 1.0f / sqrtf((float)dgo) : 0.0f;
  norm_out[i] = no;
  int dgi = hist_dst[i];
  norm_in[i] = dgi > 0 ? 1.0f / sqrtf((float)dgi) : 0.0f;
  float4 a = *reinterpret_cast<const float4*>(n_feat + (size_t)i * 8);
  float4 b = *reinterpret_cast<const float4*>(n_feat + (size_t)i * 8 + 4);
  a.x *= no; a.y *= no; a.z *= no; a.w *= no;
  b.x *= no; b.y *= no; b.z *= no; b.w *= no;
  *reinterpret_cast<float4*>(xs + (size_t)i * 8) = a;
  *reinterpret_cast<float4*>(xs + (size_t)i * 8 + 4) = b;
  atomicAdd(&counts[gid[i]], 1);
}

__global__ void k_invcounts(const int* __restrict__ counts, float* __restrict__ inv) {
  int g = threadIdx.x;
  if (g < NG) inv[g] = 1.0f / fmaxf((float)counts[g], 1.0f);
}

// CSR gather-aggregate: agg[i] = (sum_{e in in(i)} xs[src(e)]) * norm_in[i]
// one thread per (node, float4 chunk)
template <int D>
__global__ void k_agg(const float* __restrict__ xs, const int* __restrict__ csr,
                      const int* __restrict__ row_ptr, const float* __restrict__ norm_in,
                      float* __restrict__ agg) {
  constexpr int C = D / 4;
  int t = blockIdx.x * blockDim.x + threadIdx.x;
  if (t >= NN * C) return;
  int i = t / C;
  int c = t % C;
  int e0 = row_ptr[i], e1 = row_ptr[i + 1];
  float4 acc = {0.f, 0.f, 0.f, 0.f};
  for (int e = e0; e < e1; ++e) {
    int s = csr[e];
    float4 v = *reinterpret_cast<const float4*>(xs + (size_t)s * D + c * 4);
    acc.x += v.x; acc.y += v.y; acc.z += v.z; acc.w += v.w;
  }
  float ni = norm_in[i];
  acc.x *= ni; acc.y *= ni; acc.z *= ni; acc.w *= ni;
  *reinterpret_cast<float4*>(agg + (size_t)t * 4) = acc;
}

// node update: xs_out = relu(agg @ W + b) * norm_out   (agg already * norm_in)
template <int DIN, int DOUT>
__global__ void k_layer(const float* __restrict__ agg, const float* __restrict__ norm_out,
                        const float* __restrict__ W, const float* __restrict__ b,
                        float* __restrict__ xs_out) {
  int i = blockIdx.x * blockDim.x + threadIdx.x;
  if (i >= NN) return;
  float x[DIN];
#pragma unroll
  for (int k = 0; k < DIN; ++k) x[k] = agg[(size_t)i * DIN + k];
  float no = norm_out[i];
#pragma unroll
  for (int j = 0; j < DOUT; ++j) {
    float acc = b[j];
#pragma unroll
    for (int k = 0; k < DIN; ++k) acc = fmaf(x[k], W[k * DOUT + j], acc);
    acc = fmaxf(acc, 0.f);
    xs_out[(size_t)i * DOUT + j] = acc * no;
  }
}

// fused: layer3 matmul (32->128) + maxpool(2) + MLP 64->128->64->32->10 + graph mean
__global__ void __launch_bounds__(256) k_tail_mlp(
    const float* __restrict__ agg, const int* __restrict__ gid,
    const float* __restrict__ W3, const float* __restrict__ b3,
    const float* __restrict__ fW1, const float* __restrict__ fb1,
    const float* __restrict__ fW2, const float* __restrict__ fb2,
    const float* __restrict__ fW3, const float* __restrict__ fb3,
    const float* __restrict__ fW4, const float* __restrict__ fb4,
    const float* __restrict__ inv_counts, float* __restrict__ out) {
  int i = blockIdx.x * blockDim.x + threadIdx.x;
  if (i >= NN) return;
  float x[32];
#pragma unroll
  for (int k = 0; k < 32; k += 4) {
    float4 v = *reinterpret_cast<const float4*>(agg + (size_t)i * 32 + k);
    x[k] = v.x; x[k + 1] = v.y; x[k + 2] = v.z; x[k + 3] = v.w;
  }
  // W3 (no relu) + maxpool(2) -> p[64]
  float p[64];
#pragma unroll
  for (int j = 0; j < 64; ++j) {
    float a0 = b3[2 * j], a1 = b3[2 * j + 1];
#pragma unroll
    for (int k = 0; k < 32; ++k) {
      a0 = fmaf(x[k], W3[k * 128 + 2 * j], a0);
      a1 = fmaf(x[k], W3[k * 128 + 2 * j + 1], a1);
    }
    p[j] = fmaxf(a0, a1);
  }
  // fc1: 64 -> 128, relu
  float q[128];
#pragma unroll
  for (int j = 0; j < 128; ++j) {
    float a = fb1[j];
#pragma unroll
    for (int k = 0; k < 64; ++k) a = fmaf(p[k], fW1[k * 128 + j], a);
    q[j] = fmaxf(a, 0.f);
  }
  // fc2: 128 -> 64, relu (reuse p)
  float r[64];
#pragma unroll
  for (int j = 0; j < 64; ++j) {
    float a = fb2[j];
#pragma unroll
    for (int k = 0; k < 128; ++k) a = fmaf(q[k], fW2[k * 64 + j], a);
    r[j] = fmaxf(a, 0.f);
  }
  // fc3: 64 -> 32, relu
  float s[32];
#pragma unroll
  for (int j = 0; j < 32; ++j) {
    float a = fb3[j];
#pragma unroll
    for (int k = 0; k < 64; ++k) a = fmaf(r[k], fW3[k * 32 + j], a);
    s[j] = fmaxf(a, 0.f);
  }
  // fc4: 32 -> 10, graph-mean accumulate
  int g = gid[i];
  float ic = inv_counts[g];
#pragma unroll
  for (int j = 0; j < 10; ++j) {
    float a = fb4[j];
#pragma unroll
    for (int k = 0; k < 32; ++k) a = fmaf(s[k], fW4[k * 10 + j], a);
    atomicAdd(&out[g * 10 + j], a * ic);
  }
}

extern "C" void kernel_launch(void* const* d_in, const int* in_sizes, int n_in,
                              void* d_out, int out_size, void* d_ws, size_t ws_size,
                              hipStream_t stream) {
  const int* src = (const int*)d_in[0];
  const int* dst = (const int*)d_in[1];
  const int* gid = (const int*)d_in[2];
  const float* n_feat = (const float*)d_in[3];
  const float* W1 = (const float*)d_in[4];
  const float* b1 = (const float*)d_in[5];
  const float* W2 = (const float*)d_in[6];
  const float* b2 = (const float*)d_in[7];
  const float* W3 = (const float*)d_in[8];
  const float* b3 = (const float*)d_in[9];
  const float* fW1 = (const float*)d_in[10];
  const float* fb1 = (const float*)d_in[11];
  const float* fW2 = (const float*)d_in[12];
  const float* fb2 = (const float*)d_in[13];
  const float* fW3 = (const float*)d_in[14];
  const float* fb3 = (const float*)d_in[15];
  const float* fW4 = (const float*)d_in[16];
  const float* fb4 = (const float*)d_in[17];
  float* out = (float*)d_out;

  float* ws = (float*)d_ws;
  float* norm_out = ws + OFF_NORM_OUT;
  float* norm_in = ws + OFF_NORM_IN;
  float* inv_cnt = ws + OFF_INVC;
  int* counts = (int*)(ws + OFF_COUNTS);
  int* row_ptr = (int*)(ws + OFF_ROWPTR);
  int* csr = (int*)(ws + OFF_CSR);
  float* agg = ws + OFF_AGG;
  float* buf = ws + OFF_BUF;
  // setup-phase aliases inside the agg region
  int* hist_src = (int*)agg;
  int* hist_dst = (int*)agg + NN;
  int* next = (int*)agg + 2 * NN;

  hipMemsetAsync(hist_src, 0, 2 * NN * sizeof(int), stream);        // hist_src+hist_dst
  hipMemsetAsync(counts, 0, 256 * sizeof(int), stream);
  hipMemsetAsync(out, 0, (size_t)out_size * sizeof(float), stream);

  k_hist<<<(NE + 255) / 256, 256, 0, stream>>>(src, dst, hist_src, hist_dst);
  k_scan<<<1, SCAN_T, 0, stream>>>(hist_dst, row_ptr, next);
  k_fill<<<(NE + 255) / 256, 256, 0, stream>>>(src, dst, next, csr);
  k_norm_scale<<<(NN + 255) / 256, 256, 0, stream>>>(n_feat, gid, hist_src, hist_dst,
                                                     norm_out, norm_in, counts, buf);
  k_invcounts<<<1, 256, 0, stream>>>(counts, inv_cnt);

  // layer 1: gather-agg d=8, then 8->16 relu
  k_agg<8><<<(NN * 2 + 255) / 256, 256, 0, stream>>>(buf, csr, row_ptr, norm_in, agg);
  k_layer<8, 16><<<(NN + 255) / 256, 256, 0, stream>>>(agg, norm_out, W1, b1, buf);

  // layer 2: gather-agg d=16, then 16->32 relu
  k_agg<16><<<(NN * 4 + 255) / 256, 256, 0, stream>>>(buf, csr, row_ptr, norm_in, agg);
  k_layer<16, 32><<<(NN + 255) / 256, 256, 0, stream>>>(agg, norm_out, W2, b2, buf);

  // layer 3: gather-agg d=32, then fused tail (W3+maxpool+MLP+graph-mean)
  k_agg<32><<<(NN * 8 + 255) / 256, 256, 0, stream>>>(buf, csr, row_ptr, norm_in, agg);
  k_tail_mlp<<<(NN + 255) / 256, 256, 0, stream>>>(agg, gid, W3, b3, fW1, fb1, fW2, fb2,
                                                   fW3, fb3, fW4, fb4, inv_cnt, out);
}

// Round 3
// 879.663 us; speedup vs baseline: 3.1050x; 3.1050x over previous
//
#include <hip/hip_runtime.h>

#define NN 100000
#define NE 1600000
#define NG 256

// ---------------------------------------------------------------------------
// Workspace layout (4-byte words). All buffers 16B-aligned (offsets % 4 == 0).
//   norm_out  : [0, NN)                      float
//   norm_in   : [NN, 2NN)                    float
//   inv_cnt   : [2NN, 2NN+256)               float
//   counts    : [2NN+256, 2NN+512)           int
//   row_ptr   : [2NN+512, 3NN+516)           int (NN+1 used, padded)
//   csr_src   : [3NN+516, +NE)               int
//   agg       : [A, A+32NN)                  float (setup aliases: hist_src=A,
//                                            hist_dst=A+NN, next=A+2NN)
//   buf       : [B, B+32NN)                  float (xs0 -> xs1 -> xs2)
// ---------------------------------------------------------------------------
#define OFF_NORM_OUT 0
#define OFF_NORM_IN  (NN)
#define OFF_INVC     (2 * NN)
#define OFF_COUNTS   (2 * NN + 256)
#define OFF_ROWPTR   (2 * NN + 512)
#define OFF_CSR      (3 * NN + 516)
#define OFF_AGG      (3 * NN + 516 + NE)
#define OFF_BUF      (3 * NN + 516 + NE + 32 * NN)

__global__ void k_hist(const int* __restrict__ src, const int* __restrict__ dst,
                       int* __restrict__ hist_src, int* __restrict__ hist_dst) {
  int e = blockIdx.x * blockDim.x + threadIdx.x;
  if (e < NE) {
    atomicAdd(&hist_src[src[e]], 1);
    atomicAdd(&hist_dst[dst[e]], 1);
  }
}

// single-block exclusive scan of hist_dst -> row_ptr (and a copy into next)
#define SCAN_T 1024
__global__ void __launch_bounds__(SCAN_T) k_scan(const int* __restrict__ hist,
                                                 int* __restrict__ row_ptr,
                                                 int* __restrict__ next) {
  __shared__ int ssum[SCAN_T];
  int t = threadIdx.x;
  constexpr int CH = (NN + SCAN_T - 1) / SCAN_T;  // 98
  int lo = t * CH;
  int hi = min(lo + CH, NN);
  int s = 0;
  for (int i = lo; i < hi; ++i) s += hist[i];
  ssum[t] = s;
  __syncthreads();
  int incl = s;
  for (int off = 1; off < SCAN_T; off <<= 1) {
    int o = (t >= off) ? ssum[t - off] : 0;
    __syncthreads();
    incl += o;
    ssum[t] = incl;
    __syncthreads();
  }
  int base = incl - s;  // exclusive prefix
  for (int i = lo; i < hi; ++i) {
    row_ptr[i] = base;
    next[i] = base;
    base += hist[i];
  }
  if (t == 0) row_ptr[NN] = NE;
}

__global__ void k_fill(const int* __restrict__ src, const int* __restrict__ dst,
                       int* __restrict__ next, int* __restrict__ csr) {
  int e = blockIdx.x * blockDim.x + threadIdx.x;
  if (e < NE) {
    int slot = atomicAdd(&next[dst[e]], 1);
    csr[slot] = src[e];
  }
}

// norms from int degree hists, xs0 = n_feat * norm_out, graph histogram
__global__ void k_norm_scale(const float* __restrict__ n_feat, const int* __restrict__ gid,
                             const int* __restrict__ hist_src, const int* __restrict__ hist_dst,
                             float* __restrict__ norm_out, float* __restrict__ norm_in,
                             int* __restrict__ counts, float* __restrict__ xs) {
  int i = blockIdx.x * blockDim.x + threadIdx.x;
  if (i >= NN) return;
  int dgo = hist_src[i];
  float no = dgo > 0 ? 1.0f / sqrtf((float)dgo) : 0.0f;
  norm_out[i] = no;
  int dgi = hist_dst[i];
  norm_in[i] = dgi > 0 ? 1.0f / sqrtf((float)dgi) : 0.0f;
  float4 a = *reinterpret_cast<const float4*>(n_feat + (size_t)i * 8);
  float4 b = *reinterpret_cast<const float4*>(n_feat + (size_t)i * 8 + 4);
  a.x *= no; a.y *= no; a.z *= no; a.w *= no;
  b.x *= no; b.y *= no; b.z *= no; b.w *= no;
  *reinterpret_cast<float4*>(xs + (size_t)i * 8) = a;
  *reinterpret_cast<float4*>(xs + (size_t)i * 8 + 4) = b;
  atomicAdd(&counts[gid[i]], 1);
}

__global__ void k_invcounts(const int* __restrict__ counts, float* __restrict__ inv) {
  int g = threadIdx.x;
  if (g < NG) inv[g] = 1.0f / fmaxf((float)counts[g], 1.0f);
}

// CSR gather-aggregate: agg[i] = (sum_{e in in(i)} xs[src(e)]) * norm_in[i]
template <int D>
__global__ void k_agg(const float* __restrict__ xs, const int* __restrict__ csr,
                      const int* __restrict__ row_ptr, const float* __restrict__ norm_in,
                      float* __restrict__ agg) {
  constexpr int C = D / 4;
  int t = blockIdx.x * blockDim.x + threadIdx.x;
  if (t >= NN * C) return;
  int i = t / C;
  int c = t % C;
  int e0 = row_ptr[i], e1 = row_ptr[i + 1];
  float4 acc = {0.f, 0.f, 0.f, 0.f};
  for (int e = e0; e < e1; ++e) {
    int s = csr[e];
    float4 v = *reinterpret_cast<const float4*>(xs + (size_t)s * D + c * 4);
    acc.x += v.x; acc.y += v.y; acc.z += v.z; acc.w += v.w;
  }
  float ni = norm_in[i];
  acc.x *= ni; acc.y *= ni; acc.z *= ni; acc.w *= ni;
  *reinterpret_cast<float4*>(agg + (size_t)t * 4) = acc;
}

// node update: xs_out = relu(agg @ W + b) * norm_out   (agg already * norm_in)
template <int DIN, int DOUT>
__global__ void k_layer(const float* __restrict__ agg, const float* __restrict__ norm_out,
                        const float* __restrict__ W, const float* __restrict__ b,
                        float* __restrict__ xs_out) {
  int i = blockIdx.x * blockDim.x + threadIdx.x;
  if (i >= NN) return;
  float x[DIN];
#pragma unroll
  for (int k = 0; k < DIN; ++k) x[k] = agg[(size_t)i * DIN + k];
  float no = norm_out[i];
#pragma unroll
  for (int j = 0; j < DOUT; ++j) {
    float acc = b[j];
#pragma unroll
    for (int k = 0; k < DIN; ++k) acc = fmaf(x[k], W[k * DOUT + j], acc);
    acc = fmaxf(acc, 0.f);
    xs_out[(size_t)i * DOUT + j] = acc * no;
  }
}

// ---------------------------------------------------------------------------
// Fused tail: per block of 32 nodes, run W3+maxpool, fc1..fc4, graph-mean.
// Activations ping-pong between two padded LDS buffers; weights staged in LDS.
// ---------------------------------------------------------------------------
__device__ __forceinline__ void stage_w(float* __restrict__ dst, const float* __restrict__ src,
                                        int n, int t) {
  for (int i = t * 4; i < n; i += 1024) {
    float4 v = *reinterpret_cast<const float4*>(src + i);
    *reinterpret_cast<float4*>(dst + i) = v;
  }
}

// C[32 x DOUT] = A[32 x DIN] @ W[DIN x DOUT] + b; per-thread tile MT x NT.
template <int DIN, int DOUT, int MT, int NT, bool RELU, bool POOL>
__device__ __forceinline__ void phase_gemm(const float* __restrict__ A, int SA,
                                           float* __restrict__ B, int SB,
                                           const float* __restrict__ wl,
                                           const float* __restrict__ bias, int t) {
  constexpr int OG = DOUT / NT;
  static_assert((32 / MT) * OG == 256, "tile mapping must cover 256 threads");
  int og = t % OG;
  int ng = t / OG;
  int n0 = ng * MT;
  int j0 = og * NT;
  float acc[MT][NT];
#pragma unroll
  for (int m = 0; m < MT; ++m)
#pragma unroll
    for (int jj = 0; jj < NT; ++jj) acc[m][jj] = bias[j0 + jj];
#pragma unroll 4
  for (int k = 0; k < DIN; k += 2) {
    float w0[NT], w1[NT];
    if constexpr (NT == 4) {
      float4 a4 = *reinterpret_cast<const float4*>(wl + k * DOUT + j0);
      float4 b4 = *reinterpret_cast<const float4*>(wl + (k + 1) * DOUT + j0);
      w0[0] = a4.x; w0[1] = a4.y; w0[2] = a4.z; w0[3] = a4.w;
      w1[0] = b4.x; w1[1] = b4.y; w1[2] = b4.z; w1[3] = b4.w;
    } else {
      float2 a2 = *reinterpret_cast<const float2*>(wl + k * DOUT + j0);
      float2 b2 = *reinterpret_cast<const float2*>(wl + (k + 1) * DOUT + j0);
      w0[0] = a2.x; w0[1] = a2.y;
      w1[0] = b2.x; w1[1] = b2.y;
    }
#pragma unroll
    for (int m = 0; m < MT; ++m) {
      float2 a = *reinterpret_cast<const float2*>(A + (n0 + m) * SA + k);
#pragma unroll
      for (int jj = 0; jj < NT; ++jj) {
        acc[m][jj] = fmaf(a.x, w0[jj], acc[m][jj]);
        acc[m][jj] = fmaf(a.y, w1[jj], acc[m][jj]);
      }
    }
  }
  if constexpr (POOL) {
#pragma unroll
    for (int m = 0; m < MT; ++m)
#pragma unroll
      for (int h = 0; h < NT / 2; ++h)
        B[(n0 + m) * SB + og * (NT / 2) + h] = fmaxf(acc[m][2 * h], acc[m][2 * h + 1]);
  } else {
#pragma unroll
    for (int m = 0; m < MT; ++m)
#pragma unroll
      for (int jj = 0; jj < NT; ++jj) {
        float v = acc[m][jj];
        if constexpr (RELU) v = fmaxf(v, 0.f);
        B[(n0 + m) * SB + j0 + jj] = v;
      }
  }
}

__global__ void __launch_bounds__(256) k_tail_fused(
    const float* __restrict__ agg, const int* __restrict__ gid,
    const float* __restrict__ W3, const float* __restrict__ b3,
    const float* __restrict__ fW1, const float* __restrict__ fb1,
    const float* __restrict__ fW2, const float* __restrict__ fb2,
    const float* __restrict__ fW3, const float* __restrict__ fb3,
    const float* __restrict__ fW4, const float* __restrict__ fb4,
    const float* __restrict__ inv_counts, float* __restrict__ out) {
  __shared__ __align__(16) float Abuf[32 * 130];  // holds x(34) / q(130) / s(34)
  __shared__ __align__(16) float Bbuf[32 * 66];   // holds p(66) / r(66) / t(12)
  __shared__ __align__(16) float wbuf[8192];
  __shared__ int sgid[32];
  int t = threadIdx.x;
  int nb = blockIdx.x * 32;

  // stage x = agg[32 nodes x 32] into Abuf (stride 34)
  {
    float4 v = *reinterpret_cast<const float4*>(agg + (size_t)nb * 32 + t * 4);
    int n = t / 8, k = (t % 8) * 4;
    Abuf[n * 34 + k + 0] = v.x;
    Abuf[n * 34 + k + 1] = v.y;
    Abuf[n * 34 + k + 2] = v.z;
    Abuf[n * 34 + k + 3] = v.w;
  }
  if (t < 32) sgid[t] = gid[nb + t];
  stage_w(wbuf, W3, 32 * 128, t);
  __syncthreads();
  // layer3 (32->128, +bias, no relu) fused with maxpool(2) -> p[32][64]
  phase_gemm<32, 128, 4, 4, false, true>(Abuf, 34, Bbuf, 66, wbuf, b3, t);
  __syncthreads();
  stage_w(wbuf, fW1, 64 * 128, t);
  __syncthreads();
  phase_gemm<64, 128, 4, 4, true, false>(Bbuf, 66, Abuf, 130, wbuf, fb1, t);
  __syncthreads();
  stage_w(wbuf, fW2, 128 * 64, t);
  __syncthreads();
  phase_gemm<128, 64, 2, 4, true, false>(Abuf, 130, Bbuf, 66, wbuf, fb2, t);
  __syncthreads();
  stage_w(wbuf, fW3, 64 * 32, t);
  __syncthreads();
  phase_gemm<64, 32, 2, 2, true, false>(Bbuf, 66, Abuf, 34, wbuf, fb3, t);
  __syncthreads();
  stage_w(wbuf, fW4, 32 * 10, t);
  __syncthreads();
  // fc4: 32 -> 10 into Bbuf (stride 12)
  for (int idx = t; idx < 320; idx += 256) {
    int n = idx / 10, j = idx % 10;
    float a = fb4[j];
#pragma unroll
    for (int k = 0; k < 32; ++k) a = fmaf(Abuf[n * 34 + k], wbuf[k * 10 + j], a);
    Bbuf[n * 12 + j] = a;
  }
  __syncthreads();
  // segmented graph-mean reduce (gids sorted): one atomic per (segment, j)
  if (t < 10) {
    int g = sgid[0];
    float run = 0.f;
    for (int n = 0; n < 32; ++n) {
      run += Bbuf[n * 12 + t];
      bool last = (n == 31) || (sgid[n + 1] != g);
      if (last) {
        atomicAdd(&out[g * 10 + t], run * inv_counts[g]);
        run = 0.f;
        if (n < 31) g = sgid[n + 1];
      }
    }
  }
}

extern "C" void kernel_launch(void* const* d_in, const int* in_sizes, int n_in,
                              void* d_out, int out_size, void* d_ws, size_t ws_size,
                              hipStream_t stream) {
  const int* src = (const int*)d_in[0];
  const int* dst = (const int*)d_in[1];
  const int* gid = (const int*)d_in[2];
  const float* n_feat = (const float*)d_in[3];
  const float* W1 = (const float*)d_in[4];
  const float* b1 = (const float*)d_in[5];
  const float* W2 = (const float*)d_in[6];
  const float* b2 = (const float*)d_in[7];
  const float* W3 = (const float*)d_in[8];
  const float* b3 = (const float*)d_in[9];
  const float* fW1 = (const float*)d_in[10];
  const float* fb1 = (const float*)d_in[11];
  const float* fW2 = (const float*)d_in[12];
  const float* fb2 = (const float*)d_in[13];
  const float* fW3 = (const float*)d_in[14];
  const float* fb3 = (const float*)d_in[15];
  const float* fW4 = (const float*)d_in[16];
  const float* fb4 = (const float*)d_in[17];
  float* out = (float*)d_out;

  float* ws = (float*)d_ws;
  float* norm_out = ws + OFF_NORM_OUT;
  float* norm_in = ws + OFF_NORM_IN;
  float* inv_cnt = ws + OFF_INVC;
  int* counts = (int*)(ws + OFF_COUNTS);
  int* row_ptr = (int*)(ws + OFF_ROWPTR);
  int* csr = (int*)(ws + OFF_CSR);
  float* agg = ws + OFF_AGG;
  float* buf = ws + OFF_BUF;
  // setup-phase aliases inside the agg region
  int* hist_src = (int*)agg;
  int* hist_dst = (int*)agg + NN;
  int* next = (int*)agg + 2 * NN;

  hipMemsetAsync(hist_src, 0, 2 * NN * sizeof(int), stream);
  hipMemsetAsync(counts, 0, 256 * sizeof(int), stream);
  hipMemsetAsync(out, 0, (size_t)out_size * sizeof(float), stream);

  k_hist<<<(NE + 255) / 256, 256, 0, stream>>>(src, dst, hist_src, hist_dst);
  k_scan<<<1, SCAN_T, 0, stream>>>(hist_dst, row_ptr, next);
  k_fill<<<(NE + 255) / 256, 256, 0, stream>>>(src, dst, next, csr);
  k_norm_scale<<<(NN + 255) / 256, 256, 0, stream>>>(n_feat, gid, hist_src, hist_dst,
                                                     norm_out, norm_in, counts, buf);
  k_invcounts<<<1, 256, 0, stream>>>(counts, inv_cnt);

  // layer 1: gather-agg d=8, then 8->16 relu
  k_agg<8><<<(NN * 2 + 255) / 256, 256, 0, stream>>>(buf, csr, row_ptr, norm_in, agg);
  k_layer<8, 16><<<(NN + 255) / 256, 256, 0, stream>>>(agg, norm_out, W1, b1, buf);

  // layer 2: gather-agg d=16, then 16->32 relu
  k_agg<16><<<(NN * 4 + 255) / 256, 256, 0, stream>>>(buf, csr, row_ptr, norm_in, agg);
  k_layer<16, 32><<<(NN + 255) / 256, 256, 0, stream>>>(agg, norm_out, W2, b2, buf);

  // layer 3: gather-agg d=32, then fused tail (W3+maxpool+MLP+graph-mean)
  k_agg<32><<<(NN * 8 + 255) / 256, 256, 0, stream>>>(buf, csr, row_ptr, norm_in, agg);
  k_tail_fused<<<NN / 32, 256, 0, stream>>>(agg, gid, W3, b3, fW1, fb1, fW2, fb2,
                                            fW3, fb3, fW4, fb4, inv_cnt, out);
}

// Round 4
// 663.269 us; speedup vs baseline: 4.1180x; 1.3263x over previous
//
#include <hip/hip_runtime.h>

#define NN 100000
#define NE 1600000
#define NG 256

// ---------------------------------------------------------------------------
// Workspace layout (4-byte words). All buffers 16B-aligned (offsets % 4 == 0).
//   norm_out  : [0, NN)                      float
//   norm_in   : [NN, 2NN)                    float
//   inv_cnt   : [2NN, 2NN+256)               float
//   counts    : [2NN+256, 2NN+512)           int
//   row_ptr   : [2NN+512, 3NN+516)           int (NN+1 used, padded)
//   csr_src   : [3NN+516, +NE)               int
//   agg       : [A, A+32NN)                  float (setup aliases: hist_src=A,
//                                            hist_dst=A+NN, next=A+2NN)
//   buf       : [B, B+32NN)                  float (xs0 -> xs1 -> xs2)
//   lscan     : [C, C+NN)                    int
//   part      : [C+NN, C+NN+128)             int
// ---------------------------------------------------------------------------
#define OFF_NORM_OUT 0
#define OFF_NORM_IN  (NN)
#define OFF_INVC     (2 * NN)
#define OFF_COUNTS   (2 * NN + 256)
#define OFF_ROWPTR   (2 * NN + 512)
#define OFF_CSR      (3 * NN + 516)
#define OFF_AGG      (3 * NN + 516 + NE)
#define OFF_BUF      (OFF_AGG + 32 * NN)
#define OFF_LSCAN    (OFF_BUF + 32 * NN)
#define OFF_PART     (OFF_LSCAN + NN)

#define SCB 1024
#define NSB ((NN + SCB - 1) / SCB)  // 98

__global__ void k_hist(const int* __restrict__ src, const int* __restrict__ dst,
                       int* __restrict__ hist_src, int* __restrict__ hist_dst) {
  int e = blockIdx.x * blockDim.x + threadIdx.x;
  if (e < NE) {
    atomicAdd(&hist_src[src[e]], 1);
    atomicAdd(&hist_dst[dst[e]], 1);
  }
}

// hierarchical scan, pass 1: per-block scan + block totals
__global__ void __launch_bounds__(SCB) k_scan1(const int* __restrict__ hist,
                                               int* __restrict__ lscan,
                                               int* __restrict__ part) {
  __shared__ int tmp[SCB];
  int t = threadIdx.x;
  int i = blockIdx.x * SCB + t;
  int v = (i < NN) ? hist[i] : 0;
  int incl = v;
  tmp[t] = v;
  __syncthreads();
  for (int off = 1; off < SCB; off <<= 1) {
    int o = (t >= off) ? tmp[t - off] : 0;
    __syncthreads();
    incl += o;
    tmp[t] = incl;
    __syncthreads();
  }
  if (i < NN) lscan[i] = incl - v;  // exclusive within block
  if (t == SCB - 1) part[blockIdx.x] = incl;  // block total
}

// pass 2: scan the 98 block totals (single small block)
__global__ void __launch_bounds__(128) k_scan2(int* __restrict__ part) {
  __shared__ int tmp[128];
  int t = threadIdx.x;
  int v = (t < NSB) ? part[t] : 0;
  int incl = v;
  tmp[t] = v;
  __syncthreads();
  for (int off = 1; off < 128; off <<= 1) {
    int o = (t >= off) ? tmp[t - off] : 0;
    __syncthreads();
    incl += o;
    tmp[t] = incl;
    __syncthreads();
  }
  if (t < NSB) part[t] = incl - v;  // exclusive block base
}

// pass 3: add block base, write row_ptr and next
__global__ void __launch_bounds__(SCB) k_scan3(const int* __restrict__ lscan,
                                               const int* __restrict__ part,
                                               int* __restrict__ row_ptr,
                                               int* __restrict__ next) {
  int i = blockIdx.x * SCB + threadIdx.x;
  if (i < NN) {
    int rp = lscan[i] + part[blockIdx.x];
    row_ptr[i] = rp;
    next[i] = rp;
  }
  if (i == 0) row_ptr[NN] = NE;
}

__global__ void k_fill(const int* __restrict__ src, const int* __restrict__ dst,
                       int* __restrict__ next, int* __restrict__ csr) {
  int e = blockIdx.x * blockDim.x + threadIdx.x;
  if (e < NE) {
    int slot = atomicAdd(&next[dst[e]], 1);
    csr[slot] = src[e];
  }
}

// norms from int degree hists, xs0 = n_feat * norm_out, graph histogram
__global__ void k_norm_scale(const float* __restrict__ n_feat, const int* __restrict__ gid,
                             const int* __restrict__ hist_src, const int* __restrict__ hist_dst,
                             float* __restrict__ norm_out, float* __restrict__ norm_in,
                             int* __restrict__ counts, float* __restrict__ xs) {
  int i = blockIdx.x * blockDim.x + threadIdx.x;
  if (i >= NN) return;
  int dgo = hist_src[i];
  float no = dgo > 0 ? 1.0f / sqrtf((float)dgo) : 0.0f;
  norm_out[i] = no;
  int dgi = hist_dst[i];
  norm_in[i] = dgi > 0 ? 1.0f / sqrtf((float)dgi) : 0.0f;
  float4 a = *reinterpret_cast<const float4*>(n_feat + (size_t)i * 8);
  float4 b = *reinterpret_cast<const float4*>(n_feat + (size_t)i * 8 + 4);
  a.x *= no; a.y *= no; a.z *= no; a.w *= no;
  b.x *= no; b.y *= no; b.z *= no; b.w *= no;
  *reinterpret_cast<float4*>(xs + (size_t)i * 8) = a;
  *reinterpret_cast<float4*>(xs + (size_t)i * 8 + 4) = b;
  atomicAdd(&counts[gid[i]], 1);
}

__global__ void k_invcounts(const int* __restrict__ counts, float* __restrict__ inv) {
  int g = threadIdx.x;
  if (g < NG) inv[g] = 1.0f / fmaxf((float)counts[g], 1.0f);
}

// CSR gather-aggregate: agg[i] = (sum_{e in in(i)} xs[src(e)]) * norm_in[i]
template <int D>
__global__ void k_agg(const float* __restrict__ xs, const int* __restrict__ csr,
                      const int* __restrict__ row_ptr, const float* __restrict__ norm_in,
                      float* __restrict__ agg) {
  constexpr int C = D / 4;
  int t = blockIdx.x * blockDim.x + threadIdx.x;
  if (t >= NN * C) return;
  int i = t / C;
  int c = t % C;
  int e0 = row_ptr[i], e1 = row_ptr[i + 1];
  float4 acc = {0.f, 0.f, 0.f, 0.f};
  for (int e = e0; e < e1; ++e) {
    int s = csr[e];
    float4 v = *reinterpret_cast<const float4*>(xs + (size_t)s * D + c * 4);
    acc.x += v.x; acc.y += v.y; acc.z += v.z; acc.w += v.w;
  }
  float ni = norm_in[i];
  acc.x *= ni; acc.y *= ni; acc.z *= ni; acc.w *= ni;
  *reinterpret_cast<float4*>(agg + (size_t)t * 4) = acc;
}

// node update: xs_out = relu(agg @ W + b) * norm_out   (agg already * norm_in)
template <int DIN, int DOUT>
__global__ void k_layer(const float* __restrict__ agg, const float* __restrict__ norm_out,
                        const float* __restrict__ W, const float* __restrict__ b,
                        float* __restrict__ xs_out) {
  int i = blockIdx.x * blockDim.x + threadIdx.x;
  if (i >= NN) return;
  float x[DIN];
#pragma unroll
  for (int k = 0; k < DIN; ++k) x[k] = agg[(size_t)i * DIN + k];
  float no = norm_out[i];
#pragma unroll
  for (int j = 0; j < DOUT; ++j) {
    float acc = b[j];
#pragma unroll
    for (int k = 0; k < DIN; ++k) acc = fmaf(x[k], W[k * DOUT + j], acc);
    acc = fmaxf(acc, 0.f);
    xs_out[(size_t)i * DOUT + j] = acc * no;
  }
}

// ---------------------------------------------------------------------------
// Fused tail: per block of 32 nodes, run W3+maxpool, fc1..fc4, graph-mean.
// ---------------------------------------------------------------------------
__device__ __forceinline__ void stage_w(float* __restrict__ dst, const float* __restrict__ src,
                                        int n, int t) {
  for (int i = t * 4; i < n; i += 1024) {
    float4 v = *reinterpret_cast<const float4*>(src + i);
    *reinterpret_cast<float4*>(dst + i) = v;
  }
}

// C[32 x DOUT] = A[32 x DIN] @ W[DIN x DOUT] + b; per-thread tile MT x NT.
template <int DIN, int DOUT, int MT, int NT, bool RELU, bool POOL>
__device__ __forceinline__ void phase_gemm(const float* __restrict__ A, int SA,
                                           float* __restrict__ B, int SB,
                                           const float* __restrict__ wl,
                                           const float* __restrict__ bias, int t) {
  constexpr int OG = DOUT / NT;
  static_assert((32 / MT) * OG == 256, "tile mapping must cover 256 threads");
  int og = t % OG;
  int ng = t / OG;
  int n0 = ng * MT;
  int j0 = og * NT;
  float acc[MT][NT];
#pragma unroll
  for (int m = 0; m < MT; ++m)
#pragma unroll
    for (int jj = 0; jj < NT; ++jj) acc[m][jj] = bias[j0 + jj];
#pragma unroll 4
  for (int k = 0; k < DIN; k += 2) {
    float w0[NT], w1[NT];
    if constexpr (NT == 4) {
      float4 a4 = *reinterpret_cast<const float4*>(wl + k * DOUT + j0);
      float4 b4 = *reinterpret_cast<const float4*>(wl + (k + 1) * DOUT + j0);
      w0[0] = a4.x; w0[1] = a4.y; w0[2] = a4.z; w0[3] = a4.w;
      w1[0] = b4.x; w1[1] = b4.y; w1[2] = b4.z; w1[3] = b4.w;
    } else {
      float2 a2 = *reinterpret_cast<const float2*>(wl + k * DOUT + j0);
      float2 b2 = *reinterpret_cast<const float2*>(wl + (k + 1) * DOUT + j0);
      w0[0] = a2.x; w0[1] = a2.y;
      w1[0] = b2.x; w1[1] = b2.y;
    }
#pragma unroll
    for (int m = 0; m < MT; ++m) {
      float2 a = *reinterpret_cast<const float2*>(A + (n0 + m) * SA + k);
#pragma unroll
      for (int jj = 0; jj < NT; ++jj) {
        acc[m][jj] = fmaf(a.x, w0[jj], acc[m][jj]);
        acc[m][jj] = fmaf(a.y, w1[jj], acc[m][jj]);
      }
    }
  }
  if constexpr (POOL) {
#pragma unroll
    for (int m = 0; m < MT; ++m)
#pragma unroll
      for (int h = 0; h < NT / 2; ++h)
        B[(n0 + m) * SB + og * (NT / 2) + h] = fmaxf(acc[m][2 * h], acc[m][2 * h + 1]);
  } else {
#pragma unroll
    for (int m = 0; m < MT; ++m)
#pragma unroll
      for (int jj = 0; jj < NT; ++jj) {
        float v = acc[m][jj];
        if constexpr (RELU) v = fmaxf(v, 0.f);
        B[(n0 + m) * SB + j0 + jj] = v;
      }
  }
}

__global__ void __launch_bounds__(256) k_tail_fused(
    const float* __restrict__ agg, const int* __restrict__ gid,
    const float* __restrict__ W3, const float* __restrict__ b3,
    const float* __restrict__ fW1, const float* __restrict__ fb1,
    const float* __restrict__ fW2, const float* __restrict__ fb2,
    const float* __restrict__ fW3, const float* __restrict__ fb3,
    const float* __restrict__ fW4, const float* __restrict__ fb4,
    const float* __restrict__ inv_counts, float* __restrict__ out) {
  __shared__ __align__(16) float Abuf[32 * 130];  // holds x(34) / q(130) / s(34)
  __shared__ __align__(16) float Bbuf[32 * 66];   // holds p(66) / r(66) / t(12)
  __shared__ __align__(16) float wbuf[8192];
  __shared__ int sgid[32];
  int t = threadIdx.x;
  int nb = blockIdx.x * 32;

  // stage x = agg[32 nodes x 32] into Abuf (stride 34)
  {
    float4 v = *reinterpret_cast<const float4*>(agg + (size_t)nb * 32 + t * 4);
    int n = t / 8, k = (t % 8) * 4;
    Abuf[n * 34 + k + 0] = v.x;
    Abuf[n * 34 + k + 1] = v.y;
    Abuf[n * 34 + k + 2] = v.z;
    Abuf[n * 34 + k + 3] = v.w;
  }
  if (t < 32) sgid[t] = gid[nb + t];
  stage_w(wbuf, W3, 32 * 128, t);
  __syncthreads();
  // layer3 (32->128, +bias, no relu) fused with maxpool(2) -> p[32][64]
  phase_gemm<32, 128, 4, 4, false, true>(Abuf, 34, Bbuf, 66, wbuf, b3, t);
  __syncthreads();
  stage_w(wbuf, fW1, 64 * 128, t);
  __syncthreads();
  phase_gemm<64, 128, 4, 4, true, false>(Bbuf, 66, Abuf, 130, wbuf, fb1, t);
  __syncthreads();
  stage_w(wbuf, fW2, 128 * 64, t);
  __syncthreads();
  phase_gemm<128, 64, 2, 4, true, false>(Abuf, 130, Bbuf, 66, wbuf, fb2, t);
  __syncthreads();
  stage_w(wbuf, fW3, 64 * 32, t);
  __syncthreads();
  phase_gemm<64, 32, 2, 2, true, false>(Bbuf, 66, Abuf, 34, wbuf, fb3, t);
  __syncthreads();
  stage_w(wbuf, fW4, 32 * 10, t);
  __syncthreads();
  // fc4: 32 -> 10 into Bbuf (stride 12)
  for (int idx = t; idx < 320; idx += 256) {
    int n = idx / 10, j = idx % 10;
    float a = fb4[j];
#pragma unroll
    for (int k = 0; k < 32; ++k) a = fmaf(Abuf[n * 34 + k], wbuf[k * 10 + j], a);
    Bbuf[n * 12 + j] = a;
  }
  __syncthreads();
  // segmented graph-mean reduce (gids sorted): one atomic per (segment, j)
  if (t < 10) {
    int g = sgid[0];
    float run = 0.f;
    for (int n = 0; n < 32; ++n) {
      run += Bbuf[n * 12 + t];
      bool last = (n == 31) || (sgid[n + 1] != g);
      if (last) {
        atomicAdd(&out[g * 10 + t], run * inv_counts[g]);
        run = 0.f;
        if (n < 31) g = sgid[n + 1];
      }
    }
  }
}

extern "C" void kernel_launch(void* const* d_in, const int* in_sizes, int n_in,
                              void* d_out, int out_size, void* d_ws, size_t ws_size,
                              hipStream_t stream) {
  const int* src = (const int*)d_in[0];
  const int* dst = (const int*)d_in[1];
  const int* gid = (const int*)d_in[2];
  const float* n_feat = (const float*)d_in[3];
  const float* W1 = (const float*)d_in[4];
  const float* b1 = (const float*)d_in[5];
  const float* W2 = (const float*)d_in[6];
  const float* b2 = (const float*)d_in[7];
  const float* W3 = (const float*)d_in[8];
  const float* b3 = (const float*)d_in[9];
  const float* fW1 = (const float*)d_in[10];
  const float* fb1 = (const float*)d_in[11];
  const float* fW2 = (const float*)d_in[12];
  const float* fb2 = (const float*)d_in[13];
  const float* fW3 = (const float*)d_in[14];
  const float* fb3 = (const float*)d_in[15];
  const float* fW4 = (const float*)d_in[16];
  const float* fb4 = (const float*)d_in[17];
  float* out = (float*)d_out;

  float* ws = (float*)d_ws;
  float* norm_out = ws + OFF_NORM_OUT;
  float* norm_in = ws + OFF_NORM_IN;
  float* inv_cnt = ws + OFF_INVC;
  int* counts = (int*)(ws + OFF_COUNTS);
  int* row_ptr = (int*)(ws + OFF_ROWPTR);
  int* csr = (int*)(ws + OFF_CSR);
  float* agg = ws + OFF_AGG;
  float* buf = ws + OFF_BUF;
  int* lscan = (int*)(ws + OFF_LSCAN);
  int* part = (int*)(ws + OFF_PART);
  // setup-phase aliases inside the agg region
  int* hist_src = (int*)agg;
  int* hist_dst = (int*)agg + NN;
  int* next = (int*)agg + 2 * NN;

  hipMemsetAsync(hist_src, 0, 2 * NN * sizeof(int), stream);
  hipMemsetAsync(counts, 0, 256 * sizeof(int), stream);
  hipMemsetAsync(out, 0, (size_t)out_size * sizeof(float), stream);

  k_hist<<<(NE + 255) / 256, 256, 0, stream>>>(src, dst, hist_src, hist_dst);
  k_scan1<<<NSB, SCB, 0, stream>>>(hist_dst, lscan, part);
  k_scan2<<<1, 128, 0, stream>>>(part);
  k_scan3<<<NSB, SCB, 0, stream>>>(lscan, part, row_ptr, next);
  k_fill<<<(NE + 255) / 256, 256, 0, stream>>>(src, dst, next, csr);
  k_norm_scale<<<(NN + 255) / 256, 256, 0, stream>>>(n_feat, gid, hist_src, hist_dst,
                                                     norm_out, norm_in, counts, buf);
  k_invcounts<<<1, 256, 0, stream>>>(counts, inv_cnt);

  // layer 1: gather-agg d=8, then 8->16 relu
  k_agg<8><<<(NN * 2 + 255) / 256, 256, 0, stream>>>(buf, csr, row_ptr, norm_in, agg);
  k_layer<8, 16><<<(NN + 255) / 256, 256, 0, stream>>>(agg, norm_out, W1, b1, buf);

  // layer 2: gather-agg d=16, then 16->32 relu
  k_agg<16><<<(NN * 4 + 255) / 256, 256, 0, stream>>>(buf, csr, row_ptr, norm_in, agg);
  k_layer<16, 32><<<(NN + 255) / 256, 256, 0, stream>>>(agg, norm_out, W2, b2, buf);

  // layer 3: gather-agg d=32, then fused tail (W3+maxpool+MLP+graph-mean)
  k_agg<32><<<(NN * 8 + 255) / 256, 256, 0, stream>>>(buf, csr, row_ptr, norm_in, agg);
  k_tail_fused<<<NN / 32, 256, 0, stream>>>(agg, gid, W3, b3, fW1, fb1, fW2, fb2,
                                            fW3, fb3, fW4, fb4, inv_cnt, out);
}

// Round 5
// 513.121 us; speedup vs baseline: 5.3230x; 1.2926x over previous
//
#include <hip/hip_runtime.h>

#define NN 100000
#define NE 1600000
#define NG 256

// ---------------------------------------------------------------------------
// Workspace layout (4-byte words). All buffers 16B-aligned (offsets % 4 == 0).
//   norm_out  : [0, NN)                      float
//   norm_in   : [NN, 2NN)                    float
//   inv_cnt   : [2NN, 2NN+256)               float
//   row_ptr   : [2NN+512, 3NN+516)           int (NN+1 used, padded)
//   csr_src   : [3NN+516, +NE)               int
//   agg       : [A, A+32NN)                  float (setup aliases: hist_src=A,
//                                            hist_dst=A+NN, next=A+2NN)
//   buf       : [B, B+32NN)                  float (xs0 -> xs1 -> xs2)
//   lscan     : [C, C+NN)                    int
//   part      : [C+NN, C+NN+128)             int
// ---------------------------------------------------------------------------
#define OFF_NORM_OUT 0
#define OFF_NORM_IN  (NN)
#define OFF_INVC     (2 * NN)
#define OFF_ROWPTR   (2 * NN + 512)
#define OFF_CSR      (3 * NN + 516)
#define OFF_AGG      (3 * NN + 516 + NE)
#define OFF_BUF      (OFF_AGG + 32 * NN)
#define OFF_LSCAN    (OFF_BUF + 32 * NN)
#define OFF_PART     (OFF_LSCAN + NN)

#define SCB 1024
#define NSB ((NN + SCB - 1) / SCB)  // 98

__global__ void k_hist(const int* __restrict__ src, const int* __restrict__ dst,
                       int* __restrict__ hist_src, int* __restrict__ hist_dst) {
  int e = blockIdx.x * blockDim.x + threadIdx.x;
  if (e < NE) {
    atomicAdd(&hist_src[src[e]], 1);
    atomicAdd(&hist_dst[dst[e]], 1);
  }
}

// hierarchical scan, pass 1: per-block scan + block totals
__global__ void __launch_bounds__(SCB) k_scan1(const int* __restrict__ hist,
                                               int* __restrict__ lscan,
                                               int* __restrict__ part) {
  __shared__ int tmp[SCB];
  int t = threadIdx.x;
  int i = blockIdx.x * SCB + t;
  int v = (i < NN) ? hist[i] : 0;
  int incl = v;
  tmp[t] = v;
  __syncthreads();
  for (int off = 1; off < SCB; off <<= 1) {
    int o = (t >= off) ? tmp[t - off] : 0;
    __syncthreads();
    incl += o;
    tmp[t] = incl;
    __syncthreads();
  }
  if (i < NN) lscan[i] = incl - v;  // exclusive within block
  if (t == SCB - 1) part[blockIdx.x] = incl;  // block total
}

// pass 2: scan the 98 block totals (single small block)
__global__ void __launch_bounds__(128) k_scan2(int* __restrict__ part) {
  __shared__ int tmp[128];
  int t = threadIdx.x;
  int v = (t < NSB) ? part[t] : 0;
  int incl = v;
  tmp[t] = v;
  __syncthreads();
  for (int off = 1; off < 128; off <<= 1) {
    int o = (t >= off) ? tmp[t - off] : 0;
    __syncthreads();
    incl += o;
    tmp[t] = incl;
    __syncthreads();
  }
  if (t < NSB) part[t] = incl - v;  // exclusive block base
}

// pass 3: add block base, write row_ptr and next
__global__ void __launch_bounds__(SCB) k_scan3(const int* __restrict__ lscan,
                                               const int* __restrict__ part,
                                               int* __restrict__ row_ptr,
                                               int* __restrict__ next) {
  int i = blockIdx.x * SCB + threadIdx.x;
  if (i < NN) {
    int rp = lscan[i] + part[blockIdx.x];
    row_ptr[i] = rp;
    next[i] = rp;
  }
  if (i == 0) row_ptr[NN] = NE;
}

__global__ void k_fill(const int* __restrict__ src, const int* __restrict__ dst,
                       int* __restrict__ next, int* __restrict__ csr) {
  int e = blockIdx.x * blockDim.x + threadIdx.x;
  if (e < NE) {
    int slot = atomicAdd(&next[dst[e]], 1);
    csr[slot] = src[e];
  }
}

// norms from int degree hists, xs0 = n_feat * norm_out (no atomics)
__global__ void k_norm_scale(const float* __restrict__ n_feat,
                             const int* __restrict__ hist_src, const int* __restrict__ hist_dst,
                             float* __restrict__ norm_out, float* __restrict__ norm_in,
                             float* __restrict__ xs) {
  int i = blockIdx.x * blockDim.x + threadIdx.x;
  if (i >= NN) return;
  int dgo = hist_src[i];
  float no = dgo > 0 ? 1.0f / sqrtf((float)dgo) : 0.0f;
  norm_out[i] = no;
  int dgi = hist_dst[i];
  norm_in[i] = dgi > 0 ? 1.0f / sqrtf((float)dgi) : 0.0f;
  float4 a = *reinterpret_cast<const float4*>(n_feat + (size_t)i * 8);
  float4 b = *reinterpret_cast<const float4*>(n_feat + (size_t)i * 8 + 4);
  a.x *= no; a.y *= no; a.z *= no; a.w *= no;
  b.x *= no; b.y *= no; b.z *= no; b.w *= no;
  *reinterpret_cast<float4*>(xs + (size_t)i * 8) = a;
  *reinterpret_cast<float4*>(xs + (size_t)i * 8 + 4) = b;
}

// graph sizes via binary search on the SORTED gid array: no atomics at all.
__global__ void __launch_bounds__(NG) k_graphinfo(const int* __restrict__ gid,
                                                  float* __restrict__ inv) {
  int g = threadIdx.x;  // one thread per graph
  // lower_bound(gid, g) and lower_bound(gid, g+1)
  int lo0 = 0, hi0 = NN;
  while (lo0 < hi0) { int m = (lo0 + hi0) >> 1; if (gid[m] < g) lo0 = m + 1; else hi0 = m; }
  int lo1 = lo0, hi1 = NN;
  while (lo1 < hi1) { int m = (lo1 + hi1) >> 1; if (gid[m] < g + 1) lo1 = m + 1; else hi1 = m; }
  int c = lo1 - lo0;
  inv[g] = 1.0f / fmaxf((float)c, 1.0f);
}

// CSR gather-aggregate: agg[i] = (sum_{e in in(i)} xs[src(e)]) * norm_in[i]
template <int D>
__global__ void k_agg(const float* __restrict__ xs, const int* __restrict__ csr,
                      const int* __restrict__ row_ptr, const float* __restrict__ norm_in,
                      float* __restrict__ agg) {
  constexpr int C = D / 4;
  int t = blockIdx.x * blockDim.x + threadIdx.x;
  if (t >= NN * C) return;
  int i = t / C;
  int c = t % C;
  int e0 = row_ptr[i], e1 = row_ptr[i + 1];
  float4 acc = {0.f, 0.f, 0.f, 0.f};
  for (int e = e0; e < e1; ++e) {
    int s = csr[e];
    float4 v = *reinterpret_cast<const float4*>(xs + (size_t)s * D + c * 4);
    acc.x += v.x; acc.y += v.y; acc.z += v.z; acc.w += v.w;
  }
  float ni = norm_in[i];
  acc.x *= ni; acc.y *= ni; acc.z *= ni; acc.w *= ni;
  *reinterpret_cast<float4*>(agg + (size_t)t * 4) = acc;
}

// node update: xs_out = relu(agg @ W + b) * norm_out   (agg already * norm_in)
template <int DIN, int DOUT>
__global__ void k_layer(const float* __restrict__ agg, const float* __restrict__ norm_out,
                        const float* __restrict__ W, const float* __restrict__ b,
                        float* __restrict__ xs_out) {
  int i = blockIdx.x * blockDim.x + threadIdx.x;
  if (i >= NN) return;
  float x[DIN];
#pragma unroll
  for (int k = 0; k < DIN; ++k) x[k] = agg[(size_t)i * DIN + k];
  float no = norm_out[i];
#pragma unroll
  for (int j = 0; j < DOUT; ++j) {
    float acc = b[j];
#pragma unroll
    for (int k = 0; k < DIN; ++k) acc = fmaf(x[k], W[k * DOUT + j], acc);
    acc = fmaxf(acc, 0.f);
    xs_out[(size_t)i * DOUT + j] = acc * no;
  }
}

// ---------------------------------------------------------------------------
// Fused tail: per block of 32 nodes, run W3+maxpool, fc1..fc4, graph-mean.
// ---------------------------------------------------------------------------
__device__ __forceinline__ void stage_w(float* __restrict__ dst, const float* __restrict__ src,
                                        int n, int t) {
  for (int i = t * 4; i < n; i += 1024) {
    float4 v = *reinterpret_cast<const float4*>(src + i);
    *reinterpret_cast<float4*>(dst + i) = v;
  }
}

// C[32 x DOUT] = A[32 x DIN] @ W[DIN x DOUT] + b; per-thread tile MT x NT.
template <int DIN, int DOUT, int MT, int NT, bool RELU, bool POOL>
__device__ __forceinline__ void phase_gemm(const float* __restrict__ A, int SA,
                                           float* __restrict__ B, int SB,
                                           const float* __restrict__ wl,
                                           const float* __restrict__ bias, int t) {
  constexpr int OG = DOUT / NT;
  static_assert((32 / MT) * OG == 256, "tile mapping must cover 256 threads");
  int og = t % OG;
  int ng = t / OG;
  int n0 = ng * MT;
  int j0 = og * NT;
  float acc[MT][NT];
#pragma unroll
  for (int m = 0; m < MT; ++m)
#pragma unroll
    for (int jj = 0; jj < NT; ++jj) acc[m][jj] = bias[j0 + jj];
#pragma unroll 4
  for (int k = 0; k < DIN; k += 2) {
    float w0[NT], w1[NT];
    if constexpr (NT == 4) {
      float4 a4 = *reinterpret_cast<const float4*>(wl + k * DOUT + j0);
      float4 b4 = *reinterpret_cast<const float4*>(wl + (k + 1) * DOUT + j0);
      w0[0] = a4.x; w0[1] = a4.y; w0[2] = a4.z; w0[3] = a4.w;
      w1[0] = b4.x; w1[1] = b4.y; w1[2] = b4.z; w1[3] = b4.w;
    } else {
      float2 a2 = *reinterpret_cast<const float2*>(wl + k * DOUT + j0);
      float2 b2 = *reinterpret_cast<const float2*>(wl + (k + 1) * DOUT + j0);
      w0[0] = a2.x; w0[1] = a2.y;
      w1[0] = b2.x; w1[1] = b2.y;
    }
#pragma unroll
    for (int m = 0; m < MT; ++m) {
      float2 a = *reinterpret_cast<const float2*>(A + (n0 + m) * SA + k);
#pragma unroll
      for (int jj = 0; jj < NT; ++jj) {
        acc[m][jj] = fmaf(a.x, w0[jj], acc[m][jj]);
        acc[m][jj] = fmaf(a.y, w1[jj], acc[m][jj]);
      }
    }
  }
  if constexpr (POOL) {
#pragma unroll
    for (int m = 0; m < MT; ++m)
#pragma unroll
      for (int h = 0; h < NT / 2; ++h)
        B[(n0 + m) * SB + og * (NT / 2) + h] = fmaxf(acc[m][2 * h], acc[m][2 * h + 1]);
  } else {
#pragma unroll
    for (int m = 0; m < MT; ++m)
#pragma unroll
      for (int jj = 0; jj < NT; ++jj) {
        float v = acc[m][jj];
        if constexpr (RELU) v = fmaxf(v, 0.f);
        B[(n0 + m) * SB + j0 + jj] = v;
      }
  }
}

__global__ void __launch_bounds__(256) k_tail_fused(
    const float* __restrict__ agg, const int* __restrict__ gid,
    const float* __restrict__ W3, const float* __restrict__ b3,
    const float* __restrict__ fW1, const float* __restrict__ fb1,
    const float* __restrict__ fW2, const float* __restrict__ fb2,
    const float* __restrict__ fW3, const float* __restrict__ fb3,
    const float* __restrict__ fW4, const float* __restrict__ fb4,
    const float* __restrict__ inv_counts, float* __restrict__ out) {
  __shared__ __align__(16) float Abuf[32 * 130];  // holds x(34) / q(130) / s(34)
  __shared__ __align__(16) float Bbuf[32 * 66];   // holds p(66) / r(66) / t(12)
  __shared__ __align__(16) float wbuf[8192];
  __shared__ int sgid[32];
  int t = threadIdx.x;
  int nb = blockIdx.x * 32;

  // stage x = agg[32 nodes x 32] into Abuf (stride 34)
  {
    float4 v = *reinterpret_cast<const float4*>(agg + (size_t)nb * 32 + t * 4);
    int n = t / 8, k = (t % 8) * 4;
    Abuf[n * 34 + k + 0] = v.x;
    Abuf[n * 34 + k + 1] = v.y;
    Abuf[n * 34 + k + 2] = v.z;
    Abuf[n * 34 + k + 3] = v.w;
  }
  if (t < 32) sgid[t] = gid[nb + t];
  stage_w(wbuf, W3, 32 * 128, t);
  __syncthreads();
  // layer3 (32->128, +bias, no relu) fused with maxpool(2) -> p[32][64]
  phase_gemm<32, 128, 4, 4, false, true>(Abuf, 34, Bbuf, 66, wbuf, b3, t);
  __syncthreads();
  stage_w(wbuf, fW1, 64 * 128, t);
  __syncthreads();
  phase_gemm<64, 128, 4, 4, true, false>(Bbuf, 66, Abuf, 130, wbuf, fb1, t);
  __syncthreads();
  stage_w(wbuf, fW2, 128 * 64, t);
  __syncthreads();
  phase_gemm<128, 64, 2, 4, true, false>(Abuf, 130, Bbuf, 66, wbuf, fb2, t);
  __syncthreads();
  stage_w(wbuf, fW3, 64 * 32, t);
  __syncthreads();
  phase_gemm<64, 32, 2, 2, true, false>(Bbuf, 66, Abuf, 34, wbuf, fb3, t);
  __syncthreads();
  stage_w(wbuf, fW4, 32 * 10, t);
  __syncthreads();
  // fc4: 32 -> 10 into Bbuf (stride 12)
  for (int idx = t; idx < 320; idx += 256) {
    int n = idx / 10, j = idx % 10;
    float a = fb4[j];
#pragma unroll
    for (int k = 0; k < 32; ++k) a = fmaf(Abuf[n * 34 + k], wbuf[k * 10 + j], a);
    Bbuf[n * 12 + j] = a;
  }
  __syncthreads();
  // segmented graph-mean reduce (gids sorted): one atomic per (segment, j)
  if (t < 10) {
    int g = sgid[0];
    float run = 0.f;
    for (int n = 0; n < 32; ++n) {
      run += Bbuf[n * 12 + t];
      bool last = (n == 31) || (sgid[n + 1] != g);
      if (last) {
        atomicAdd(&out[g * 10 + t], run * inv_counts[g]);
        run = 0.f;
        if (n < 31) g = sgid[n + 1];
      }
    }
  }
}

extern "C" void kernel_launch(void* const* d_in, const int* in_sizes, int n_in,
                              void* d_out, int out_size, void* d_ws, size_t ws_size,
                              hipStream_t stream) {
  const int* src = (const int*)d_in[0];
  const int* dst = (const int*)d_in[1];
  const int* gid = (const int*)d_in[2];
  const float* n_feat = (const float*)d_in[3];
  const float* W1 = (const float*)d_in[4];
  const float* b1 = (const float*)d_in[5];
  const float* W2 = (const float*)d_in[6];
  const float* b2 = (const float*)d_in[7];
  const float* W3 = (const float*)d_in[8];
  const float* b3 = (const float*)d_in[9];
  const float* fW1 = (const float*)d_in[10];
  const float* fb1 = (const float*)d_in[11];
  const float* fW2 = (const float*)d_in[12];
  const float* fb2 = (const float*)d_in[13];
  const float* fW3 = (const float*)d_in[14];
  const float* fb3 = (const float*)d_in[15];
  const float* fW4 = (const float*)d_in[16];
  const float* fb4 = (const float*)d_in[17];
  float* out = (float*)d_out;

  float* ws = (float*)d_ws;
  float* norm_out = ws + OFF_NORM_OUT;
  float* norm_in = ws + OFF_NORM_IN;
  float* inv_cnt = ws + OFF_INVC;
  int* row_ptr = (int*)(ws + OFF_ROWPTR);
  int* csr = (int*)(ws + OFF_CSR);
  float* agg = ws + OFF_AGG;
  float* buf = ws + OFF_BUF;
  int* lscan = (int*)(ws + OFF_LSCAN);
  int* part = (int*)(ws + OFF_PART);
  // setup-phase aliases inside the agg region
  int* hist_src = (int*)agg;
  int* hist_dst = (int*)agg + NN;
  int* next = (int*)agg + 2 * NN;

  hipMemsetAsync(hist_src, 0, 2 * NN * sizeof(int), stream);
  hipMemsetAsync(out, 0, (size_t)out_size * sizeof(float), stream);

  k_hist<<<(NE + 255) / 256, 256, 0, stream>>>(src, dst, hist_src, hist_dst);
  k_graphinfo<<<1, NG, 0, stream>>>(gid, inv_cnt);
  k_scan1<<<NSB, SCB, 0, stream>>>(hist_dst, lscan, part);
  k_scan2<<<1, 128, 0, stream>>>(part);
  k_scan3<<<NSB, SCB, 0, stream>>>(lscan, part, row_ptr, next);
  k_fill<<<(NE + 255) / 256, 256, 0, stream>>>(src, dst, next, csr);
  k_norm_scale<<<(NN + 255) / 256, 256, 0, stream>>>(n_feat, hist_src, hist_dst,
                                                     norm_out, norm_in, buf);

  // layer 1: gather-agg d=8, then 8->16 relu
  k_agg<8><<<(NN * 2 + 255) / 256, 256, 0, stream>>>(buf, csr, row_ptr, norm_in, agg);
  k_layer<8, 16><<<(NN + 255) / 256, 256, 0, stream>>>(agg, norm_out, W1, b1, buf);

  // layer 2: gather-agg d=16, then 16->32 relu
  k_agg<16><<<(NN * 4 + 255) / 256, 256, 0, stream>>>(buf, csr, row_ptr, norm_in, agg);
  k_layer<16, 32><<<(NN + 255) / 256, 256, 0, stream>>>(agg, norm_out, W2, b2, buf);

  // layer 3: gather-agg d=32, then fused tail (W3+maxpool+MLP+graph-mean)
  k_agg<32><<<(NN * 8 + 255) / 256, 256, 0, stream>>>(buf, csr, row_ptr, norm_in, agg);
  k_tail_fused<<<NN / 32, 256, 0, stream>>>(agg, gid, W3, b3, fW1, fb1, fW2, fb2,
                                            fW3, fb3, fW4, fb4, inv_cnt, out);
}

// Round 6
// 376.225 us; speedup vs baseline: 7.2599x; 1.3639x over previous
//
#include <hip/hip_runtime.h>

#define NN 100000
#define NE 1600000
#define NG 256

#define NB 196    // node buckets of 512 nodes
#define BSH 9     // bucket shift (512)
#define NPB 392   // partition blocks
#define EPB 4096  // edges per partition block

// ---------------------------------------------------------------------------
// Workspace layout (4-byte words). 16B alignment holds for agg/buf.
//   norm_out  : [0, NN)                      float
//   norm_in   : [NN, 2NN)                    float
//   inv_cnt   : [2NN, 2NN+256)               float
//   row_ptr   : [2NN+512, 3NN+516)           int (NN+1 used, padded)
//   csr_src   : [3NN+516, +NE)               int
//   agg       : [A, A+32NN)                  float (alias: pairs uint2[NE])
//   buf       : [B, B+32NN)                  float (alias: srcbuf int[NE])
//   cnt_dst   : [C, C+NB*NPB)                int
//   cnt_src   : [.., +NB*NPB)                int
//   bb_dst    : [.., +200)                   int (NB+1 used)
//   bb_src    : [.., +200)                   int
// ---------------------------------------------------------------------------
#define OFF_NORM_OUT 0
#define OFF_NORM_IN  (NN)
#define OFF_INVC     (2 * NN)
#define OFF_ROWPTR   (2 * NN + 512)
#define OFF_CSR      (3 * NN + 516)
#define OFF_AGG      (3 * NN + 516 + NE)
#define OFF_BUF      (OFF_AGG + 32 * NN)
#define OFF_CNTD     (OFF_BUF + 32 * NN)
#define OFF_CNTS     (OFF_CNTD + NB * NPB)
#define OFF_BBD      (OFF_CNTS + NB * NPB)
#define OFF_BBS      (OFF_BBD + 200)

// phase 1: per-(block,bucket) histograms of dst and src buckets (LDS only)
__global__ void __launch_bounds__(256) k_part_count(const int* __restrict__ src,
                                                    const int* __restrict__ dst,
                                                    int* __restrict__ cnt_dst,
                                                    int* __restrict__ cnt_src) {
  __shared__ int hd[NB], hs[NB];
  int t = threadIdx.x;
  int blk = blockIdx.x;
  for (int i = t; i < NB; i += 256) { hd[i] = 0; hs[i] = 0; }
  __syncthreads();
  int e0 = blk * EPB, e1 = min(e0 + EPB, NE);
  for (int e = e0 + t; e < e1; e += 256) {
    atomicAdd(&hd[dst[e] >> BSH], 1);
    atomicAdd(&hs[src[e] >> BSH], 1);
  }
  __syncthreads();
  for (int i = t; i < NB; i += 256) {
    cnt_dst[i * NPB + blk] = hd[i];
    cnt_src[i * NPB + blk] = hs[i];
  }
}

// phase 2: turn count matrices into exact chunk bases + bucket bases
__global__ void __launch_bounds__(256) k_chunk_scan(int* __restrict__ cnt_dst,
                                                    int* __restrict__ bb_dst,
                                                    int* __restrict__ cnt_src,
                                                    int* __restrict__ bb_src) {
  __shared__ int tot[256];
  int t = threadIdx.x;
  for (int p = 0; p < 2; ++p) {
    int* cnt = p ? cnt_src : cnt_dst;
    int* bb = p ? bb_src : bb_dst;
    int s = 0;
    if (t < NB)
      for (int k = 0; k < NPB; ++k) s += cnt[t * NPB + k];
    tot[t] = s;
    __syncthreads();
    int incl = s;
    for (int off = 1; off < 256; off <<= 1) {
      int o = (t >= off) ? tot[t - off] : 0;
      __syncthreads();
      incl += o;
      tot[t] = incl;
      __syncthreads();
    }
    int base = incl - s;  // exclusive bucket base
    if (t < NB) {
      bb[t] = base;
      int run = base;
      for (int k = 0; k < NPB; ++k) {
        int c = cnt[t * NPB + k];
        cnt[t * NPB + k] = run;
        run += c;
      }
      if (t == NB - 1) bb[NB] = run;
    }
    __syncthreads();
  }
}

// phase 3: scatter edges into bucket regions (block-private sequential cursors)
__global__ void __launch_bounds__(256) k_part_scatter(const int* __restrict__ src,
                                                      const int* __restrict__ dst,
                                                      const int* __restrict__ cnt_dst,
                                                      const int* __restrict__ cnt_src,
                                                      uint2* __restrict__ pairs,
                                                      int* __restrict__ srcbuf) {
  __shared__ int cd[NB], cs[NB];
  int t = threadIdx.x;
  int blk = blockIdx.x;
  for (int i = t; i < NB; i += 256) {
    cd[i] = cnt_dst[i * NPB + blk];
    cs[i] = cnt_src[i * NPB + blk];
  }
  __syncthreads();
  int e0 = blk * EPB, e1 = min(e0 + EPB, NE);
  for (int e = e0 + t; e < e1; e += 256) {
    int s = src[e], d = dst[e];
    int pd = atomicAdd(&cd[d >> BSH], 1);
    pairs[pd] = make_uint2((unsigned)s, (unsigned)d);
    int ps = atomicAdd(&cs[s >> BSH], 1);
    srcbuf[ps] = s;
  }
}

// phase 4: per-bucket CSR finalize: row_ptr, norm_in, csr (all bucket-local)
__global__ void __launch_bounds__(256) k_bucket_csr(const uint2* __restrict__ pairs,
                                                    const int* __restrict__ bb,
                                                    int* __restrict__ row_ptr,
                                                    float* __restrict__ norm_in,
                                                    int* __restrict__ csr) {
  __shared__ int hist[512], curs[512], pscan[256];
  int t = threadIdx.x;
  int b = blockIdx.x;
  int n0 = b << BSH;
  int ebase = bb[b], eend = bb[b + 1];
  hist[t] = 0;
  hist[t + 256] = 0;
  __syncthreads();
  for (int e = ebase + t; e < eend; e += 256)
    atomicAdd(&hist[pairs[e].y & 511], 1);
  __syncthreads();
  int s0 = hist[2 * t], s1 = hist[2 * t + 1];
  int ps = s0 + s1;
  pscan[t] = ps;
  __syncthreads();
  int incl = ps;
  for (int off = 1; off < 256; off <<= 1) {
    int o = (t >= off) ? pscan[t - off] : 0;
    __syncthreads();
    incl += o;
    pscan[t] = incl;
    __syncthreads();
  }
  int ex = incl - ps;
  curs[2 * t] = ex;
  curs[2 * t + 1] = ex + s0;
  int n = n0 + 2 * t;
  if (n < NN) {
    row_ptr[n] = ebase + ex;
    norm_in[n] = s0 > 0 ? 1.0f / sqrtf((float)s0) : 0.0f;
  }
  if (n + 1 < NN) {
    row_ptr[n + 1] = ebase + ex + s0;
    norm_in[n + 1] = s1 > 0 ? 1.0f / sqrtf((float)s1) : 0.0f;
  }
  __syncthreads();
  for (int e = ebase + t; e < eend; e += 256) {
    uint2 pr = pairs[e];
    int pos = atomicAdd(&curs[pr.y & 511], 1);
    csr[ebase + pos] = (int)pr.x;
  }
  if (b == 0 && t == 0) row_ptr[NN] = NE;
}

// phase 5: per-bucket out-degree -> norm_out
__global__ void __launch_bounds__(256) k_bucket_deg(const int* __restrict__ srcbuf,
                                                    const int* __restrict__ bb,
                                                    float* __restrict__ norm_out) {
  __shared__ int hist[512];
  int t = threadIdx.x;
  int b = blockIdx.x;
  hist[t] = 0;
  hist[t + 256] = 0;
  __syncthreads();
  int e0 = bb[b], e1 = bb[b + 1];
  for (int e = e0 + t; e < e1; e += 256)
    atomicAdd(&hist[srcbuf[e] & 511], 1);
  __syncthreads();
  int n = (b << BSH) + t;
  if (n < NN) {
    int d = hist[t];
    norm_out[n] = d > 0 ? 1.0f / sqrtf((float)d) : 0.0f;
  }
  n += 256;
  if (n < NN) {
    int d = hist[t + 256];
    norm_out[n] = d > 0 ? 1.0f / sqrtf((float)d) : 0.0f;
  }
}

// xs0 = n_feat * norm_out (pure streaming)
__global__ void k_norm_scale(const float* __restrict__ n_feat,
                             const float* __restrict__ norm_out,
                             float* __restrict__ xs) {
  int i = blockIdx.x * blockDim.x + threadIdx.x;
  if (i >= NN) return;
  float no = norm_out[i];
  float4 a = *reinterpret_cast<const float4*>(n_feat + (size_t)i * 8);
  float4 b = *reinterpret_cast<const float4*>(n_feat + (size_t)i * 8 + 4);
  a.x *= no; a.y *= no; a.z *= no; a.w *= no;
  b.x *= no; b.y *= no; b.z *= no; b.w *= no;
  *reinterpret_cast<float4*>(xs + (size_t)i * 8) = a;
  *reinterpret_cast<float4*>(xs + (size_t)i * 8 + 4) = b;
}

// graph sizes via binary search on the SORTED gid array: no atomics at all.
__global__ void __launch_bounds__(NG) k_graphinfo(const int* __restrict__ gid,
                                                  float* __restrict__ inv) {
  int g = threadIdx.x;
  int lo0 = 0, hi0 = NN;
  while (lo0 < hi0) { int m = (lo0 + hi0) >> 1; if (gid[m] < g) lo0 = m + 1; else hi0 = m; }
  int lo1 = lo0, hi1 = NN;
  while (lo1 < hi1) { int m = (lo1 + hi1) >> 1; if (gid[m] < g + 1) lo1 = m + 1; else hi1 = m; }
  int c = lo1 - lo0;
  inv[g] = 1.0f / fmaxf((float)c, 1.0f);
}

// CSR gather-aggregate: agg[i] = (sum_{e in in(i)} xs[src(e)]) * norm_in[i]
template <int D>
__global__ void k_agg(const float* __restrict__ xs, const int* __restrict__ csr,
                      const int* __restrict__ row_ptr, const float* __restrict__ norm_in,
                      float* __restrict__ agg) {
  constexpr int C = D / 4;
  int t = blockIdx.x * blockDim.x + threadIdx.x;
  if (t >= NN * C) return;
  int i = t / C;
  int c = t % C;
  int e0 = row_ptr[i], e1 = row_ptr[i + 1];
  float4 acc = {0.f, 0.f, 0.f, 0.f};
  for (int e = e0; e < e1; ++e) {
    int s = csr[e];
    float4 v = *reinterpret_cast<const float4*>(xs + (size_t)s * D + c * 4);
    acc.x += v.x; acc.y += v.y; acc.z += v.z; acc.w += v.w;
  }
  float ni = norm_in[i];
  acc.x *= ni; acc.y *= ni; acc.z *= ni; acc.w *= ni;
  *reinterpret_cast<float4*>(agg + (size_t)t * 4) = acc;
}

// node update: xs_out = relu(agg @ W + b) * norm_out   (agg already * norm_in)
template <int DIN, int DOUT>
__global__ void k_layer(const float* __restrict__ agg, const float* __restrict__ norm_out,
                        const float* __restrict__ W, const float* __restrict__ b,
                        float* __restrict__ xs_out) {
  int i = blockIdx.x * blockDim.x + threadIdx.x;
  if (i >= NN) return;
  float x[DIN];
#pragma unroll
  for (int k = 0; k < DIN; ++k) x[k] = agg[(size_t)i * DIN + k];
  float no = norm_out[i];
#pragma unroll
  for (int j = 0; j < DOUT; ++j) {
    float acc = b[j];
#pragma unroll
    for (int k = 0; k < DIN; ++k) acc = fmaf(x[k], W[k * DOUT + j], acc);
    acc = fmaxf(acc, 0.f);
    xs_out[(size_t)i * DOUT + j] = acc * no;
  }
}

// ---------------------------------------------------------------------------
// Fused tail: per block of 32 nodes, run W3+maxpool, fc1..fc4, graph-mean.
// ---------------------------------------------------------------------------
__device__ __forceinline__ void stage_w(float* __restrict__ dst, const float* __restrict__ src,
                                        int n, int t) {
  for (int i = t * 4; i < n; i += 1024) {
    float4 v = *reinterpret_cast<const float4*>(src + i);
    *reinterpret_cast<float4*>(dst + i) = v;
  }
}

// C[32 x DOUT] = A[32 x DIN] @ W[DIN x DOUT] + b; per-thread tile MT x NT.
template <int DIN, int DOUT, int MT, int NT, bool RELU, bool POOL>
__device__ __forceinline__ void phase_gemm(const float* __restrict__ A, int SA,
                                           float* __restrict__ B, int SB,
                                           const float* __restrict__ wl,
                                           const float* __restrict__ bias, int t) {
  constexpr int OG = DOUT / NT;
  static_assert((32 / MT) * OG == 256, "tile mapping must cover 256 threads");
  int og = t % OG;
  int ng = t / OG;
  int n0 = ng * MT;
  int j0 = og * NT;
  float acc[MT][NT];
#pragma unroll
  for (int m = 0; m < MT; ++m)
#pragma unroll
    for (int jj = 0; jj < NT; ++jj) acc[m][jj] = bias[j0 + jj];
#pragma unroll 4
  for (int k = 0; k < DIN; k += 2) {
    float w0[NT], w1[NT];
    if constexpr (NT == 4) {
      float4 a4 = *reinterpret_cast<const float4*>(wl + k * DOUT + j0);
      float4 b4 = *reinterpret_cast<const float4*>(wl + (k + 1) * DOUT + j0);
      w0[0] = a4.x; w0[1] = a4.y; w0[2] = a4.z; w0[3] = a4.w;
      w1[0] = b4.x; w1[1] = b4.y; w1[2] = b4.z; w1[3] = b4.w;
    } else {
      float2 a2 = *reinterpret_cast<const float2*>(wl + k * DOUT + j0);
      float2 b2 = *reinterpret_cast<const float2*>(wl + (k + 1) * DOUT + j0);
      w0[0] = a2.x; w0[1] = a2.y;
      w1[0] = b2.x; w1[1] = b2.y;
    }
#pragma unroll
    for (int m = 0; m < MT; ++m) {
      float2 a = *reinterpret_cast<const float2*>(A + (n0 + m) * SA + k);
#pragma unroll
      for (int jj = 0; jj < NT; ++jj) {
        acc[m][jj] = fmaf(a.x, w0[jj], acc[m][jj]);
        acc[m][jj] = fmaf(a.y, w1[jj], acc[m][jj]);
      }
    }
  }
  if constexpr (POOL) {
#pragma unroll
    for (int m = 0; m < MT; ++m)
#pragma unroll
      for (int h = 0; h < NT / 2; ++h)
        B[(n0 + m) * SB + og * (NT / 2) + h] = fmaxf(acc[m][2 * h], acc[m][2 * h + 1]);
  } else {
#pragma unroll
    for (int m = 0; m < MT; ++m)
#pragma unroll
      for (int jj = 0; jj < NT; ++jj) {
        float v = acc[m][jj];
        if constexpr (RELU) v = fmaxf(v, 0.f);
        B[(n0 + m) * SB + j0 + jj] = v;
      }
  }
}

__global__ void __launch_bounds__(256) k_tail_fused(
    const float* __restrict__ agg, const int* __restrict__ gid,
    const float* __restrict__ W3, const float* __restrict__ b3,
    const float* __restrict__ fW1, const float* __restrict__ fb1,
    const float* __restrict__ fW2, const float* __restrict__ fb2,
    const float* __restrict__ fW3, const float* __restrict__ fb3,
    const float* __restrict__ fW4, const float* __restrict__ fb4,
    const float* __restrict__ inv_counts, float* __restrict__ out) {
  __shared__ __align__(16) float Abuf[32 * 130];  // holds x(34) / q(130) / s(34)
  __shared__ __align__(16) float Bbuf[32 * 66];   // holds p(66) / r(66) / t(12)
  __shared__ __align__(16) float wbuf[8192];
  __shared__ int sgid[32];
  int t = threadIdx.x;
  int nb = blockIdx.x * 32;

  {
    float4 v = *reinterpret_cast<const float4*>(agg + (size_t)nb * 32 + t * 4);
    int n = t / 8, k = (t % 8) * 4;
    Abuf[n * 34 + k + 0] = v.x;
    Abuf[n * 34 + k + 1] = v.y;
    Abuf[n * 34 + k + 2] = v.z;
    Abuf[n * 34 + k + 3] = v.w;
  }
  if (t < 32) sgid[t] = gid[nb + t];
  stage_w(wbuf, W3, 32 * 128, t);
  __syncthreads();
  phase_gemm<32, 128, 4, 4, false, true>(Abuf, 34, Bbuf, 66, wbuf, b3, t);
  __syncthreads();
  stage_w(wbuf, fW1, 64 * 128, t);
  __syncthreads();
  phase_gemm<64, 128, 4, 4, true, false>(Bbuf, 66, Abuf, 130, wbuf, fb1, t);
  __syncthreads();
  stage_w(wbuf, fW2, 128 * 64, t);
  __syncthreads();
  phase_gemm<128, 64, 2, 4, true, false>(Abuf, 130, Bbuf, 66, wbuf, fb2, t);
  __syncthreads();
  stage_w(wbuf, fW3, 64 * 32, t);
  __syncthreads();
  phase_gemm<64, 32, 2, 2, true, false>(Bbuf, 66, Abuf, 34, wbuf, fb3, t);
  __syncthreads();
  stage_w(wbuf, fW4, 32 * 10, t);
  __syncthreads();
  for (int idx = t; idx < 320; idx += 256) {
    int n = idx / 10, j = idx % 10;
    float a = fb4[j];
#pragma unroll
    for (int k = 0; k < 32; ++k) a = fmaf(Abuf[n * 34 + k], wbuf[k * 10 + j], a);
    Bbuf[n * 12 + j] = a;
  }
  __syncthreads();
  if (t < 10) {
    int g = sgid[0];
    float run = 0.f;
    for (int n = 0; n < 32; ++n) {
      run += Bbuf[n * 12 + t];
      bool last = (n == 31) || (sgid[n + 1] != g);
      if (last) {
        atomicAdd(&out[g * 10 + t], run * inv_counts[g]);
        run = 0.f;
        if (n < 31) g = sgid[n + 1];
      }
    }
  }
}

extern "C" void kernel_launch(void* const* d_in, const int* in_sizes, int n_in,
                              void* d_out, int out_size, void* d_ws, size_t ws_size,
                              hipStream_t stream) {
  const int* src = (const int*)d_in[0];
  const int* dst = (const int*)d_in[1];
  const int* gid = (const int*)d_in[2];
  const float* n_feat = (const float*)d_in[3];
  const float* W1 = (const float*)d_in[4];
  const float* b1 = (const float*)d_in[5];
  const float* W2 = (const float*)d_in[6];
  const float* b2 = (const float*)d_in[7];
  const float* W3 = (const float*)d_in[8];
  const float* b3 = (const float*)d_in[9];
  const float* fW1 = (const float*)d_in[10];
  const float* fb1 = (const float*)d_in[11];
  const float* fW2 = (const float*)d_in[12];
  const float* fb2 = (const float*)d_in[13];
  const float* fW3 = (const float*)d_in[14];
  const float* fb3 = (const float*)d_in[15];
  const float* fW4 = (const float*)d_in[16];
  const float* fb4 = (const float*)d_in[17];
  float* out = (float*)d_out;

  float* ws = (float*)d_ws;
  float* norm_out = ws + OFF_NORM_OUT;
  float* norm_in = ws + OFF_NORM_IN;
  float* inv_cnt = ws + OFF_INVC;
  int* row_ptr = (int*)(ws + OFF_ROWPTR);
  int* csr = (int*)(ws + OFF_CSR);
  float* agg = ws + OFF_AGG;
  float* buf = ws + OFF_BUF;
  int* cnt_dst = (int*)(ws + OFF_CNTD);
  int* cnt_src = (int*)(ws + OFF_CNTS);
  int* bb_dst = (int*)(ws + OFF_BBD);
  int* bb_src = (int*)(ws + OFF_BBS);
  uint2* pairs = (uint2*)agg;   // alias (2*NE words == 32*NN words)
  int* srcbuf = (int*)buf;      // alias (NE words < 32*NN words)

  hipMemsetAsync(out, 0, (size_t)out_size * sizeof(float), stream);

  k_part_count<<<NPB, 256, 0, stream>>>(src, dst, cnt_dst, cnt_src);
  k_graphinfo<<<1, NG, 0, stream>>>(gid, inv_cnt);
  k_chunk_scan<<<1, 256, 0, stream>>>(cnt_dst, bb_dst, cnt_src, bb_src);
  k_part_scatter<<<NPB, 256, 0, stream>>>(src, dst, cnt_dst, cnt_src, pairs, srcbuf);
  k_bucket_csr<<<NB, 256, 0, stream>>>(pairs, bb_dst, row_ptr, norm_in, csr);
  k_bucket_deg<<<NB, 256, 0, stream>>>(srcbuf, bb_src, norm_out);
  k_norm_scale<<<(NN + 255) / 256, 256, 0, stream>>>(n_feat, norm_out, buf);

  // layer 1: gather-agg d=8, then 8->16 relu
  k_agg<8><<<(NN * 2 + 255) / 256, 256, 0, stream>>>(buf, csr, row_ptr, norm_in, agg);
  k_layer<8, 16><<<(NN + 255) / 256, 256, 0, stream>>>(agg, norm_out, W1, b1, buf);

  // layer 2: gather-agg d=16, then 16->32 relu
  k_agg<16><<<(NN * 4 + 255) / 256, 256, 0, stream>>>(buf, csr, row_ptr, norm_in, agg);
  k_layer<16, 32><<<(NN + 255) / 256, 256, 0, stream>>>(agg, norm_out, W2, b2, buf);

  // layer 3: gather-agg d=32, then fused tail (W3+maxpool+MLP+graph-mean)
  k_agg<32><<<(NN * 8 + 255) / 256, 256, 0, stream>>>(buf, csr, row_ptr, norm_in, agg);
  k_tail_fused<<<NN / 32, 256, 0, stream>>>(agg, gid, W3, b3, fW1, fb1, fW2, fb2,
                                            fW3, fb3, fW4, fb4, inv_cnt, out);
}